// Round 4
// baseline (831.753 us; speedup 1.0000x reference)
//
#include <hip/hip_runtime.h>

typedef unsigned short u16;
using bf16x8 = __attribute__((ext_vector_type(8))) __bf16;
using f32x4  = __attribute__((ext_vector_type(4))) float;

#define BATCH 8
#define CH    256
#define NPIX  16384
#define GN_EPS   1e-5f
#define ATTN_EPS 1e-6f

__device__ __forceinline__ u16 f2bf(float f) {
  unsigned int u = __float_as_uint(f);
  u += 0x7fffu + ((u >> 16) & 1u);
  return (u16)(u >> 16);
}

// ---------------- GroupNorm stats: per (b,g) sum / sumsq ----------------
__global__ void stats_kernel(const float* __restrict__ x, float* __restrict__ sum,
                             float* __restrict__ sqs) {
  const int gi = blockIdx.x >> 3;   // 0..63  (b*8+g)
  const int sp = blockIdx.x & 7;    // split
  const float4* p = (const float4*)x + (size_t)gi * 131072 + (size_t)sp * 16384;
  float s = 0.f, ss = 0.f;
  for (int i = 0; i < 64; ++i) {
    float4 v = p[threadIdx.x + i * 256];
    s  += v.x + v.y + v.z + v.w;
    ss += v.x * v.x + v.y * v.y + v.z * v.z + v.w * v.w;
  }
  for (int off = 32; off; off >>= 1) {
    s  += __shfl_xor(s, off);
    ss += __shfl_xor(ss, off);
  }
  __shared__ float rs[4], rss[4];
  const int wave = threadIdx.x >> 6, lane = threadIdx.x & 63;
  if (!lane) { rs[wave] = s; rss[wave] = ss; }
  __syncthreads();
  if (!threadIdx.x) {
    atomicAdd(&sum[gi], rs[0] + rs[1] + rs[2] + rs[3]);
    atomicAdd(&sqs[gi], rss[0] + rss[1] + rss[2] + rss[3]);
  }
}

// ---------------- fold stats+gamma/beta into per-(b,c) scale/shift ----------------
__global__ void finalize_kernel(const float* __restrict__ sums, const float* __restrict__ sqs,
                                const float* __restrict__ gamma, const float* __restrict__ beta,
                                float* __restrict__ sA, float* __restrict__ sB) {
  const int t = blockIdx.x * 256 + threadIdx.x;  // 0..2047
  const int c = t & 255;
  const int gi = (t >> 8) * 8 + (c >> 5);
  const float inv = 1.f / 524288.f;
  const float mean = sums[gi] * inv;
  const float var = sqs[gi] * inv - mean * mean;
  const float rstd = rsqrtf(var + GN_EPS);
  const float a = rstd * gamma[c];
  sA[t] = a;
  sB[t] = beta[c] - mean * a;
}

// ---------------- fold GN into weights: Wq' = Wq*diag(sA), bq' = bq + Wq.sB ------
__global__ __launch_bounds__(256) void foldw_kernel(
    const float* __restrict__ Wq, const float* __restrict__ bq,
    const float* __restrict__ Wk, const float* __restrict__ bk,
    const float* __restrict__ sA, const float* __restrict__ sB,
    u16* __restrict__ Wqb, u16* __restrict__ Wkb,
    float* __restrict__ bqf, float* __restrict__ bkf) {
  const int b = blockIdx.x >> 4;
  const int rt = blockIdx.x & 15;
  const int tid = threadIdx.x;
  const int wave = tid >> 6, lane = tid & 63;
  const float a = sA[b * 256 + tid];
  const float s = sB[b * 256 + tid];
  __shared__ float rq[4], rk[4];
  for (int i = 0; i < 16; ++i) {
    const int row = rt * 16 + i;
    const float wq = Wq[row * 256 + tid];
    const float wk = Wk[row * 256 + tid];
    Wqb[b * 65536 + row * 256 + tid] = f2bf(wq * a);
    Wkb[b * 65536 + row * 256 + tid] = f2bf(wk * a);
    float pq = wq * s, pk = wk * s;
    for (int off = 32; off; off >>= 1) {
      pq += __shfl_xor(pq, off);
      pk += __shfl_xor(pk, off);
    }
    if (!lane) { rq[wave] = pq; rk[wave] = pk; }
    __syncthreads();
    if (!tid) {
      bqf[b * 256 + row] = bq[row] + rq[0] + rq[1] + rq[2] + rq[3];
      bkf[b * 256 + row] = bk[row] + rk[0] + rk[1] + rk[2] + rk[3];
    }
    __syncthreads();
  }
}

// ---------------- Wvt[ci][d] = Wv[d][ci] (f32 transpose) ----------------
__global__ __launch_bounds__(256) void wvt_kernel(const float* __restrict__ Wv,
                                                  float* __restrict__ Wvt) {
  __shared__ float t[16][17];
  const int ti = blockIdx.x & 15, tj = blockIdx.x >> 4;
  const int tx = threadIdx.x & 15, ty = threadIdx.x >> 4;
  t[ty][tx] = Wv[(tj * 16 + ty) * 256 + ti * 16 + tx];
  __syncthreads();
  Wvt[(ti * 16 + ty) * 256 + tj * 16 + tx] = t[tx][ty];
}

// ---------------- fused: raw x -> K conv -> Traw += K.x^T, ksum ----------------
// grid 256 = 8b x 32sp (b = bid&7, XCD-affine), 1024 threads / 16 waves.
// Wave = ONE c_out tile; its 8 Wk' fragments are EXPLICITLY register-hoisted
// (loop-invariant, +32 VGPR -> ~96 total, still 4 waves/EU) so the chunk loop
// issues ZERO weight loads.
__global__ __launch_bounds__(1024, 4) void fused_t_kernel(
    const float* __restrict__ x, const u16* __restrict__ Wkb, const float* __restrict__ bkf,
    float* __restrict__ ksum, float* __restrict__ tdst, int mode) {
  __shared__ __align__(16) u16 xnv[64 * 288];  // raw x pixel-major [p][c], c XOR-swizzled
  __shared__ __align__(16) u16 xcm[256 * 72];  // raw x c-major [c][p]
  __shared__ __align__(16) u16 Kcp[256 * 72];  // activated K, c-major [c][p]

  const int b  = blockIdx.x & 7;
  const int sp = blockIdx.x >> 3;
  const int tid = threadIdx.x;
  const int wave = tid >> 6;   // 0..15 = c_out tile
  const int lane = tid & 63;
  const int m = lane & 15;
  const int q = lane >> 4;

  const int ckg = wave >> 2;   // T: k-row tiles [4ckg..+3]
  const int cvg = wave & 3;    // T: ci tiles  [4cvg..+3]

  const float* xb = x + (size_t)b * CH * NPIX;
  const u16* Wkbb = Wkb + b * 65536;

  // ---- hoist this wave's Wk' fragments: 8 x bf16x8 = 32 VGPR, loop-invariant ----
  bf16x8 wA[8];
#pragma unroll
  for (int ks = 0; ks < 8; ++ks)
    wA[ks] = *(const bf16x8*)(Wkbb + (wave * 16 + m) * 256 + ks * 32 + q * 8);

  float biasv[4];
#pragma unroll
  for (int r = 0; r < 4; ++r) biasv[r] = bkf[b * 256 + wave * 16 + q * 4 + r];

  f32x4 accT[4][4];
#pragma unroll
  for (int i = 0; i < 4; ++i)
#pragma unroll
    for (int j = 0; j < 4; ++j) accT[i][j] = {0.f, 0.f, 0.f, 0.f};
  float ksum_acc = 0.f;

  const int p_ = tid & 63;
  const int cq = tid >> 6;  // 0..15

  for (int ch = 0; ch < 8; ++ch) {
    const int pix0 = sp * 512 + ch * 64;
    __syncthreads();  // prev T-phase reads done; buffers free
    // ---- stage raw x -> bf16, both layouts ----
#pragma unroll
    for (int i = 0; i < 4; ++i) {
      const int c = (cq + 16 * i) * 4;
      const float v0 = __builtin_nontemporal_load(&xb[(size_t)(c + 0) * NPIX + pix0 + p_]);
      const float v1 = __builtin_nontemporal_load(&xb[(size_t)(c + 1) * NPIX + pix0 + p_]);
      const float v2 = __builtin_nontemporal_load(&xb[(size_t)(c + 2) * NPIX + pix0 + p_]);
      const float v3 = __builtin_nontemporal_load(&xb[(size_t)(c + 3) * NPIX + pix0 + p_]);
      const u16 b0 = f2bf(v0), b1 = f2bf(v1), b2 = f2bf(v2), b3 = f2bf(v3);
      const unsigned int lo = (unsigned int)b0 | ((unsigned int)b1 << 16);
      const unsigned int hi = (unsigned int)b2 | ((unsigned int)b3 << 16);
      *(uint2*)&xnv[p_ * 288 + (c ^ ((p_ & 7) << 3))] = make_uint2(lo, hi);
      xcm[(c + 0) * 72 + p_] = b0;
      xcm[(c + 1) * 72 + p_] = b1;
      xcm[(c + 2) * 72 + p_] = b2;
      xcm[(c + 3) * 72 + p_] = b3;
    }
    __syncthreads();

    // ---- K = elu(Wk' . x + bk') + 1 -> Kcp ; 1 c-tile x 4 pixel tiles/wave ----
    f32x4 ac[4];
#pragma unroll
    for (int pt = 0; pt < 4; ++pt) ac[pt] = {0.f, 0.f, 0.f, 0.f};
#pragma unroll
    for (int ks = 0; ks < 8; ++ks) {
#pragma unroll
      for (int pt = 0; pt < 4; ++pt) {
        const int prow = pt * 16 + m;
        const bf16x8 bfr =
            *(const bf16x8*)&xnv[prow * 288 + ((ks * 32 + q * 8) ^ ((prow & 7) << 3))];
        ac[pt] = __builtin_amdgcn_mfma_f32_16x16x32_bf16(wA[ks], bfr, ac[pt], 0, 0, 0);
      }
    }
#pragma unroll
    for (int r = 0; r < 4; ++r) {
      const int row = wave * 16 + q * 4 + r;
#pragma unroll
      for (int pt = 0; pt < 4; ++pt) {
        float v = ac[pt][r] + biasv[r];
        v = v > 0.f ? v + 1.f : __expf(v);
        Kcp[row * 72 + pt * 16 + m] = f2bf(v);
      }
    }
    __syncthreads();  // Kcp complete

    // ---- ksum partial (from activated K in LDS) ----
    {
      const int krow = tid & 255;
      const int kseg = tid >> 8;  // 0..3 -> cols kseg*16..+15
      const bf16x8 k0 = *(const bf16x8*)&Kcp[krow * 72 + kseg * 16];
      const bf16x8 k1 = *(const bf16x8*)&Kcp[krow * 72 + kseg * 16 + 8];
      float s = 0.f;
#pragma unroll
      for (int j = 0; j < 8; ++j) s += (float)k0[j] + (float)k1[j];
      ksum_acc += s;
    }

    // ---- T += K . x^T ----
#pragma unroll
    for (int ks = 0; ks < 2; ++ks) {
      bf16x8 af[4], bfv[4];
#pragma unroll
      for (int i = 0; i < 4; ++i)
        af[i] = *(const bf16x8*)&Kcp[((4 * ckg + i) * 16 + m) * 72 + ks * 32 + q * 8];
#pragma unroll
      for (int j = 0; j < 4; ++j)
        bfv[j] = *(const bf16x8*)&xcm[((4 * cvg + j) * 16 + m) * 72 + ks * 32 + q * 8];
#pragma unroll
      for (int i = 0; i < 4; ++i)
#pragma unroll
        for (int j = 0; j < 4; ++j)
          accT[i][j] = __builtin_amdgcn_mfma_f32_16x16x32_bf16(af[i], bfv[j], accT[i][j], 0, 0, 0);
    }
  }

  // ---- block epilogue ----
  atomicAdd(&ksum[b * CH + (tid & 255)], ksum_acc);
  if (mode == 0) {
    // per-wave-contiguous: full-line 1KB/instr regular stores
    float* Tp = tdst + (size_t)blockIdx.x * 65536 + wave * 4096 + lane * 4;
#pragma unroll
    for (int i = 0; i < 4; ++i)
#pragma unroll
      for (int j = 0; j < 4; ++j)
        *(f32x4*)(Tp + (i * 4 + j) * 256) = accT[i][j];
  } else {
    float* Tb2 = tdst + (size_t)b * 65536;
#pragma unroll
    for (int i = 0; i < 4; ++i)
#pragma unroll
      for (int j = 0; j < 4; ++j)
#pragma unroll
        for (int r = 0; r < 4; ++r) {
          const int row = (4 * ckg + i) * 16 + q * 4 + r;
          const int col = (4 * cvg + j) * 16 + m;
          atomicAdd(&Tb2[row * CH + col], accT[i][j][r]);
        }
  }
}

// ---------------- Traw[b] = sum of 32 per-block partials (unpermute) ----------------
__global__ __launch_bounds__(256) void treduce_kernel(const float* __restrict__ part,
                                                      float* __restrict__ Traw) {
  const int b = blockIdx.x >> 4;
  const int w = blockIdx.x & 15;
  __shared__ float tile[64][65];
  const size_t base = (size_t)w * 4096;
  for (int k = 0; k < 16; ++k) {
    const int o = k * 256 + threadIdx.x;
    float s = 0.f;
#pragma unroll 8
    for (int sp = 0; sp < 32; ++sp)
      s += __builtin_nontemporal_load(&part[(size_t)(sp * 8 + b) * 65536 + base + o]);
    const int lanef = (o >> 2) & 63;
    const int r = o & 3;
    const int e4 = o >> 8;
    const int i = e4 >> 2, j = e4 & 3;
    const int mm = lanef & 15, qq = lanef >> 4;
    tile[i * 16 + qq * 4 + r][j * 16 + mm] = s;
  }
  __syncthreads();
  const int ckg = w >> 2, cvg = w & 3;
  float* dst = Traw + (size_t)b * 65536 + (size_t)(ckg * 64) * 256 + cvg * 64;
  const int col = threadIdx.x & 63;
  const int r0 = threadIdx.x >> 6;
#pragma unroll
  for (int k = 0; k < 16; ++k) {
    const int lr = r0 * 16 + k;
    dst[(size_t)lr * 256 + col] = tile[lr][col];
  }
}

// ---------------- m1: G = (Wp*rs) . Traw ; A1 = sA*G + sB*s1 ; s1 = (Wp*rs).ksum --
__global__ __launch_bounds__(256) void m1_kernel(
    const float* __restrict__ Wp, const float* __restrict__ Traw,
    const float* __restrict__ ksum, const float* __restrict__ sA,
    const float* __restrict__ sB, float* __restrict__ A1, float* __restrict__ s1) {
  __shared__ float WpLT[256 * 16];
  __shared__ float ksL[256];
  const int b = blockIdx.x >> 4;
  const int rt = blockIdx.x & 15;
  const int tid = threadIdx.x;
  const float kk = ksum[b * 256 + tid];
  ksL[tid] = kk;
  const float rs = 1.f / (kk + ATTN_EPS);
#pragma unroll
  for (int r = 0; r < 16; ++r)
    WpLT[tid * 16 + r] = Wp[(rt * 16 + r) * 256 + tid] * rs;
  __syncthreads();
  float acc[16], s1a[16];
#pragma unroll
  for (int r = 0; r < 16; ++r) { acc[r] = 0.f; s1a[r] = 0.f; }
  const float* Tb = Traw + (size_t)b * 65536;
  for (int k = 0; k < 256; ++k) {
    const float v = Tb[k * 256 + tid];
    const float kv = ksL[k];
#pragma unroll
    for (int r4 = 0; r4 < 4; ++r4) {
      const f32x4 w4 = *(const f32x4*)&WpLT[k * 16 + r4 * 4];
#pragma unroll
      for (int e = 0; e < 4; ++e) {
        acc[r4 * 4 + e] += w4[e] * v;
        s1a[r4 * 4 + e] += w4[e] * kv;
      }
    }
  }
  const float av = sA[b * 256 + tid], sv = sB[b * 256 + tid];
#pragma unroll
  for (int r = 0; r < 16; ++r)
    A1[(size_t)b * 65536 + (rt * 16 + r) * 256 + tid] = av * acc[r] + sv * s1a[r];
  if (tid == 0) {
#pragma unroll
    for (int r = 0; r < 16; ++r) s1[b * 256 + rt * 16 + r] = s1a[r];
  }
}

// ---------------- m2: M = A1 . Wv^T + bv*s1 -> bf16 ----------------
__global__ __launch_bounds__(256) void m2_kernel(
    const float* __restrict__ A1, const float* __restrict__ Wvt,
    const float* __restrict__ bv, const float* __restrict__ s1,
    u16* __restrict__ Mb) {
  __shared__ float ALT[256 * 16];
  const int b = blockIdx.x >> 4;
  const int rt = blockIdx.x & 15;
  const int tid = threadIdx.x;
#pragma unroll
  for (int r = 0; r < 16; ++r)
    ALT[tid * 16 + r] = A1[(size_t)b * 65536 + (rt * 16 + r) * 256 + tid];
  __syncthreads();
  float acc[16];
#pragma unroll
  for (int r = 0; r < 16; ++r) acc[r] = 0.f;
  for (int ci = 0; ci < 256; ++ci) {
    const float wv = Wvt[ci * 256 + tid];
#pragma unroll
    for (int r4 = 0; r4 < 4; ++r4) {
      const f32x4 a4 = *(const f32x4*)&ALT[ci * 16 + r4 * 4];
#pragma unroll
      for (int e = 0; e < 4; ++e) acc[r4 * 4 + e] += a4[e] * wv;
    }
  }
  const float bvd = bv[tid];
#pragma unroll
  for (int r = 0; r < 16; ++r)
    Mb[(size_t)b * 65536 + (rt * 16 + r) * 256 + tid] =
        f2bf(acc[r] + bvd * s1[b * 256 + rt * 16 + r]);
}

// ---------------- out = M . (elu(Wq'.x+bq')+1) + bp + x ----------------
// grid 1024: b = bid&7 (XCD-affine), chunk-group = bid>>3; each block does
// TWO 64-pixel chunks so the 2nd chunk's Wq'/M reads are L2-hot (halves weight
// HBM misses). 256 thr, 36KB LDS, 4 blocks/CU.
__global__ __launch_bounds__(256, 4) void out_kernel(
    const float* __restrict__ x, const u16* __restrict__ Wqb, const float* __restrict__ bqf,
    const u16* __restrict__ Mb, const float* __restrict__ bp, float* __restrict__ out) {
  __shared__ __align__(16) u16 buf[64 * 288];  // raw x pixel-major, then q pixel-major
  const int b = blockIdx.x & 7;
  const int cg = blockIdx.x >> 3;  // 0..127
  const int tid = threadIdx.x;
  const int wave = tid >> 6;  // 0..3
  const int lane = tid & 63;
  const int m = lane & 15;
  const int q = lane >> 4;

  const float* xb = x + (size_t)b * CH * NPIX;
  const u16* Wqbb = Wqb + b * 65536;
  const u16* Ab = Mb + (size_t)b * 65536;
  float* ob = out + (size_t)b * CH * NPIX;

  const int p_ = tid & 63;
  const int cq = tid >> 6;  // 0..3

  for (int cc = 0; cc < 2; ++cc) {
    const int pix0 = cg * 128 + cc * 64;
    __syncthreads();  // prev-iteration G4 buf reads done
#pragma unroll
    for (int i = 0; i < 16; ++i) {
      const int c = (cq + 4 * i) * 4;
      const float v0 = __builtin_nontemporal_load(&xb[(size_t)(c + 0) * NPIX + pix0 + p_]);
      const float v1 = __builtin_nontemporal_load(&xb[(size_t)(c + 1) * NPIX + pix0 + p_]);
      const float v2 = __builtin_nontemporal_load(&xb[(size_t)(c + 2) * NPIX + pix0 + p_]);
      const float v3 = __builtin_nontemporal_load(&xb[(size_t)(c + 3) * NPIX + pix0 + p_]);
      const unsigned int lo = (unsigned int)f2bf(v0) | ((unsigned int)f2bf(v1) << 16);
      const unsigned int hi = (unsigned int)f2bf(v2) | ((unsigned int)f2bf(v3) << 16);
      *(uint2*)&buf[p_ * 288 + (c ^ ((p_ & 7) << 3))] = make_uint2(lo, hi);
    }
    __syncthreads();

    // G3: q^T = x^T . Wq'^T  (rows = pixels, cols = c2)
    f32x4 aq[4][4];  // [pt][ct]
#pragma unroll
    for (int pt = 0; pt < 4; ++pt)
#pragma unroll
      for (int ct = 0; ct < 4; ++ct) aq[pt][ct] = {0.f, 0.f, 0.f, 0.f};
#pragma unroll
    for (int ks = 0; ks < 8; ++ks) {
      bf16x8 af[4];
#pragma unroll
      for (int pt = 0; pt < 4; ++pt) {
        const int prow = pt * 16 + m;
        af[pt] = *(const bf16x8*)&buf[prow * 288 + ((ks * 32 + q * 8) ^ ((prow & 7) << 3))];
      }
#pragma unroll
      for (int ct = 0; ct < 4; ++ct) {
        const bf16x8 bfr =
            *(const bf16x8*)(Wqbb + ((4 * wave + ct) * 16 + m) * 256 + ks * 32 + q * 8);
#pragma unroll
        for (int pt = 0; pt < 4; ++pt)
          aq[pt][ct] = __builtin_amdgcn_mfma_f32_16x16x32_bf16(af[pt], bfr, aq[pt][ct], 0, 0, 0);
      }
    }
    __syncthreads();  // all x reads done; reuse buf for q
#pragma unroll
    for (int ct = 0; ct < 4; ++ct) {
      const int c2 = (4 * wave + ct) * 16 + m;
      const float bias = bqf[b * 256 + c2];
#pragma unroll
      for (int pt = 0; pt < 4; ++pt)
#pragma unroll
        for (int r = 0; r < 4; ++r) {
          float v = aq[pt][ct][r] + bias;
          v = v > 0.f ? v + 1.f : __expf(v);
          const int prow = pt * 16 + q * 4 + r;
          buf[prow * 288 + (c2 ^ ((prow & 7) << 3))] = f2bf(v);
        }
    }
    __syncthreads();

    // G4: out = M . q
    f32x4 ao[4][4];  // [ct][pt]
#pragma unroll
    for (int ct = 0; ct < 4; ++ct)
#pragma unroll
      for (int pt = 0; pt < 4; ++pt) ao[ct][pt] = {0.f, 0.f, 0.f, 0.f};
#pragma unroll
    for (int ks = 0; ks < 8; ++ks) {
      bf16x8 af2[4];
#pragma unroll
      for (int ct = 0; ct < 4; ++ct)
        af2[ct] = *(const bf16x8*)(Ab + ((4 * wave + ct) * 16 + m) * 256 + ks * 32 + q * 8);
#pragma unroll
      for (int pt = 0; pt < 4; ++pt) {
        const int brow = pt * 16 + m;
        const bf16x8 bfr =
            *(const bf16x8*)&buf[brow * 288 + ((ks * 32 + q * 8) ^ ((brow & 7) << 3))];
#pragma unroll
        for (int ct = 0; ct < 4; ++ct)
          ao[ct][pt] = __builtin_amdgcn_mfma_f32_16x16x32_bf16(af2[ct], bfr, ao[ct][pt], 0, 0, 0);
      }
    }
#pragma unroll
    for (int ct = 0; ct < 4; ++ct)
#pragma unroll
      for (int r = 0; r < 4; ++r) {
        const int row = (4 * wave + ct) * 16 + q * 4 + r;
        const float bias = bp[row];
#pragma unroll
        for (int pt = 0; pt < 4; ++pt) {
          const int idx = row * NPIX + pix0 + pt * 16 + m;
          const float xr = __builtin_nontemporal_load(&xb[idx]);
          ob[idx] = ao[ct][pt][r] + bias + xr;  // regular store: L2 merges lines
        }
      }
  }
}

// ---------------- launch ----------------
extern "C" void kernel_launch(void* const* d_in, const int* in_sizes, int n_in,
                              void* d_out, int out_size, void* d_ws, size_t ws_size,
                              hipStream_t stream) {
  const float* x     = (const float*)d_in[0];
  const float* gamma = (const float*)d_in[1];
  const float* beta  = (const float*)d_in[2];
  const float* Wq    = (const float*)d_in[3];
  const float* bq    = (const float*)d_in[4];
  const float* Wk    = (const float*)d_in[5];
  const float* bk    = (const float*)d_in[6];
  const float* Wv    = (const float*)d_in[7];
  const float* bv    = (const float*)d_in[8];
  const float* Wp    = (const float*)d_in[9];
  const float* bp    = (const float*)d_in[10];
  float* out = (float*)d_out;

  float* wsf  = (float*)d_ws;
  float* sum  = wsf;                 // 64
  float* sqs  = wsf + 64;            // 64
  float* ksum = wsf + 128;           // 2048
  float* sA   = wsf + 2176;          // 2048
  float* sB   = wsf + 4224;          // 2048
  float* s1   = wsf + 6272;          // 2048
  float* bkf  = wsf + 8320;          // 2048
  float* bqf  = wsf + 10368;         // 2048
  float* Wvt  = wsf + 12416;         // 65536
  float* Traw = wsf + 77952;         // 524288
  float* A1   = wsf + 602240;        // 524288
  u16* Wqb = (u16*)(wsf + 1126528);  // 524288 u16
  u16* Wkb = Wqb + 524288;           // 524288 u16
  u16* Mb  = (u16*)(wsf + 1650816);  // 524288 u16 (layout ends ~7.65 MB)

  // T partials (256 x 64K floats = 64 MiB) at the 8 MiB mark, if workspace allows.
  const bool bigws = ws_size >= ((size_t)72 << 20);
  float* Tpart = bigws ? (wsf + ((size_t)1 << 21)) : Traw;
  const int mode = bigws ? 0 : 1;

  // zero atomic targets (sum/sqs/ksum); mode 1 additionally zeroes Traw.
  hipMemsetAsync(wsf, 0, (size_t)(bigws ? 2176 : 602240) * sizeof(float), stream);
  stats_kernel<<<512, 256, 0, stream>>>(x, sum, sqs);
  finalize_kernel<<<8, 256, 0, stream>>>(sum, sqs, gamma, beta, sA, sB);
  wvt_kernel<<<256, 256, 0, stream>>>(Wv, Wvt);
  foldw_kernel<<<128, 256, 0, stream>>>(Wq, bq, Wk, bk, sA, sB, Wqb, Wkb, bqf, bkf);
  fused_t_kernel<<<256, 1024, 0, stream>>>(x, Wkb, bkf, ksum, Tpart, mode);
  if (bigws) treduce_kernel<<<128, 256, 0, stream>>>(Tpart, Traw);
  m1_kernel<<<128, 256, 0, stream>>>(Wp, Traw, ksum, sA, sB, A1, s1);
  m2_kernel<<<128, 256, 0, stream>>>(A1, Wvt, bv, s1, Mb);
  out_kernel<<<1024, 256, 0, stream>>>(x, Wqb, bqf, Mb, bp, out);
}

// Round 5
// 659.730 us; speedup vs baseline: 1.2607x; 1.2607x over previous
//
#include <hip/hip_runtime.h>

typedef unsigned short u16;
using bf16x8 = __attribute__((ext_vector_type(8))) __bf16;
using f32x4  = __attribute__((ext_vector_type(4))) float;

#define BATCH 8
#define CH    256
#define NPIX  16384
#define GN_EPS   1e-5f
#define ATTN_EPS 1e-6f

__device__ __forceinline__ u16 f2bf(float f) {
  unsigned int u = __float_as_uint(f);
  u += 0x7fffu + ((u >> 16) & 1u);
  return (u16)(u >> 16);
}

// ---------------- GroupNorm stats: per (b,g) sum / sumsq ----------------
__global__ void stats_kernel(const float* __restrict__ x, float* __restrict__ sum,
                             float* __restrict__ sqs) {
  const int gi = blockIdx.x >> 3;   // 0..63  (b*8+g)
  const int sp = blockIdx.x & 7;    // split
  const float4* p = (const float4*)x + (size_t)gi * 131072 + (size_t)sp * 16384;
  float s = 0.f, ss = 0.f;
  for (int i = 0; i < 64; ++i) {
    float4 v = p[threadIdx.x + i * 256];
    s  += v.x + v.y + v.z + v.w;
    ss += v.x * v.x + v.y * v.y + v.z * v.z + v.w * v.w;
  }
  for (int off = 32; off; off >>= 1) {
    s  += __shfl_xor(s, off);
    ss += __shfl_xor(ss, off);
  }
  __shared__ float rs[4], rss[4];
  const int wave = threadIdx.x >> 6, lane = threadIdx.x & 63;
  if (!lane) { rs[wave] = s; rss[wave] = ss; }
  __syncthreads();
  if (!threadIdx.x) {
    atomicAdd(&sum[gi], rs[0] + rs[1] + rs[2] + rs[3]);
    atomicAdd(&sqs[gi], rss[0] + rss[1] + rss[2] + rss[3]);
  }
}

// ---------------- finalize (blocks 0..7) + Wv transpose (blocks 8..263) ----------
__global__ void finalize_kernel(const float* __restrict__ sums, const float* __restrict__ sqs,
                                const float* __restrict__ gamma, const float* __restrict__ beta,
                                float* __restrict__ sA, float* __restrict__ sB,
                                const float* __restrict__ Wv, float* __restrict__ Wvt) {
  if (blockIdx.x < 8) {
    const int t = blockIdx.x * 256 + threadIdx.x;  // 0..2047
    const int c = t & 255;
    const int gi = (t >> 8) * 8 + (c >> 5);
    const float inv = 1.f / 524288.f;
    const float mean = sums[gi] * inv;
    const float var = sqs[gi] * inv - mean * mean;
    const float rstd = rsqrtf(var + GN_EPS);
    const float a = rstd * gamma[c];
    sA[t] = a;
    sB[t] = beta[c] - mean * a;
  } else {
    __shared__ float t[16][17];
    const int bid = blockIdx.x - 8;
    const int ti = bid & 15, tj = bid >> 4;
    const int tx = threadIdx.x & 15, ty = threadIdx.x >> 4;
    t[ty][tx] = Wv[(tj * 16 + ty) * 256 + ti * 16 + tx];
    __syncthreads();
    Wvt[(ti * 16 + ty) * 256 + tj * 16 + tx] = t[tx][ty];
  }
}

// ---------------- fold GN into weights: Wq' = Wq*diag(sA), bq' = bq + Wq.sB ------
__global__ __launch_bounds__(256) void foldw_kernel(
    const float* __restrict__ Wq, const float* __restrict__ bq,
    const float* __restrict__ Wk, const float* __restrict__ bk,
    const float* __restrict__ sA, const float* __restrict__ sB,
    u16* __restrict__ Wqb, u16* __restrict__ Wkb,
    float* __restrict__ bqf, float* __restrict__ bkf) {
  const int b = blockIdx.x >> 4;
  const int rt = blockIdx.x & 15;
  const int tid = threadIdx.x;
  const int wave = tid >> 6, lane = tid & 63;
  const float a = sA[b * 256 + tid];
  const float s = sB[b * 256 + tid];
  __shared__ float rq[4], rk[4];
  for (int i = 0; i < 16; ++i) {
    const int row = rt * 16 + i;
    const float wq = Wq[row * 256 + tid];
    const float wk = Wk[row * 256 + tid];
    Wqb[b * 65536 + row * 256 + tid] = f2bf(wq * a);
    Wkb[b * 65536 + row * 256 + tid] = f2bf(wk * a);
    float pq = wq * s, pk = wk * s;
    for (int off = 32; off; off >>= 1) {
      pq += __shfl_xor(pq, off);
      pk += __shfl_xor(pk, off);
    }
    if (!lane) { rq[wave] = pq; rk[wave] = pk; }
    __syncthreads();
    if (!tid) {
      bqf[b * 256 + row] = bq[row] + rq[0] + rq[1] + rq[2] + rq[3];
      bkf[b * 256 + row] = bk[row] + rk[0] + rk[1] + rk[2] + rk[3];
    }
    __syncthreads();
  }
}

// ---------------- fused: raw x -> K conv -> Traw += K.x^T, ksum ----------------
// grid 256 = 8b x 32sp (b = bid&7, XCD-affine), 1024 threads / 16 waves.
// Wk' fragments register-hoisted (32 VGPR). x-stage SOFTWARE-PIPELINED:
// chunk ch+1's 16 NT loads are issued right after chunk ch's LDS writes, so
// the vmcnt wait (first use = next iter's LDS write) is covered by 64 MFMAs.
__global__ __launch_bounds__(1024, 4) void fused_t_kernel(
    const float* __restrict__ x, const u16* __restrict__ Wkb, const float* __restrict__ bkf,
    float* __restrict__ ksum, float* __restrict__ tdst, int mode) {
  __shared__ __align__(16) u16 xnv[64 * 288];  // raw x pixel-major [p][c], c XOR-swizzled
  __shared__ __align__(16) u16 xcm[256 * 72];  // raw x c-major [c][p]
  __shared__ __align__(16) u16 Kcp[256 * 72];  // activated K, c-major [c][p]

  const int b  = blockIdx.x & 7;
  const int sp = blockIdx.x >> 3;
  const int tid = threadIdx.x;
  const int wave = tid >> 6;   // 0..15 = c_out tile
  const int lane = tid & 63;
  const int m = lane & 15;
  const int q = lane >> 4;

  const int ckg = wave >> 2;   // T: k-row tiles [4ckg..+3]
  const int cvg = wave & 3;    // T: ci tiles  [4cvg..+3]

  const float* xb = x + (size_t)b * CH * NPIX;
  const u16* Wkbb = Wkb + b * 65536;

  // ---- hoist this wave's Wk' fragments: 8 x bf16x8 = 32 VGPR, loop-invariant ----
  bf16x8 wA[8];
#pragma unroll
  for (int ks = 0; ks < 8; ++ks)
    wA[ks] = *(const bf16x8*)(Wkbb + (wave * 16 + m) * 256 + ks * 32 + q * 8);

  float biasv[4];
#pragma unroll
  for (int r = 0; r < 4; ++r) biasv[r] = bkf[b * 256 + wave * 16 + q * 4 + r];

  f32x4 accT[4][4];
#pragma unroll
  for (int i = 0; i < 4; ++i)
#pragma unroll
    for (int j = 0; j < 4; ++j) accT[i][j] = {0.f, 0.f, 0.f, 0.f};
  float ksum_acc = 0.f;

  const int p_ = tid & 63;
  const int cq = tid >> 6;  // 0..15

  // ---- prologue: prefetch chunk 0 into regs (16 VGPR) ----
  float v[4][4];
  {
    const int pix0 = sp * 512;
#pragma unroll
    for (int i = 0; i < 4; ++i) {
      const int c = (cq + 16 * i) * 4;
#pragma unroll
      for (int j = 0; j < 4; ++j)
        v[i][j] = __builtin_nontemporal_load(&xb[(size_t)(c + j) * NPIX + pix0 + p_]);
    }
  }

  for (int ch = 0; ch < 8; ++ch) {
    __syncthreads();  // prev T-phase reads done; buffers free
    // ---- write prefetched regs -> LDS (both layouts) ----
#pragma unroll
    for (int i = 0; i < 4; ++i) {
      const int c = (cq + 16 * i) * 4;
      const u16 b0 = f2bf(v[i][0]), b1 = f2bf(v[i][1]), b2 = f2bf(v[i][2]), b3 = f2bf(v[i][3]);
      const unsigned int lo = (unsigned int)b0 | ((unsigned int)b1 << 16);
      const unsigned int hi = (unsigned int)b2 | ((unsigned int)b3 << 16);
      *(uint2*)&xnv[p_ * 288 + (c ^ ((p_ & 7) << 3))] = make_uint2(lo, hi);
      xcm[(c + 0) * 72 + p_] = b0;
      xcm[(c + 1) * 72 + p_] = b1;
      xcm[(c + 2) * 72 + p_] = b2;
      xcm[(c + 3) * 72 + p_] = b3;
    }
    // ---- issue next chunk's loads (latency hidden under conv+T MFMA) ----
    if (ch < 7) {
      const int pix0n = sp * 512 + (ch + 1) * 64;
#pragma unroll
      for (int i = 0; i < 4; ++i) {
        const int c = (cq + 16 * i) * 4;
#pragma unroll
        for (int j = 0; j < 4; ++j)
          v[i][j] = __builtin_nontemporal_load(&xb[(size_t)(c + j) * NPIX + pix0n + p_]);
      }
    }
    __syncthreads();

    // ---- K = elu(Wk' . x + bk') + 1 -> Kcp ; 1 c-tile x 4 pixel tiles/wave ----
    f32x4 ac[4];
#pragma unroll
    for (int pt = 0; pt < 4; ++pt) ac[pt] = {0.f, 0.f, 0.f, 0.f};
#pragma unroll
    for (int ks = 0; ks < 8; ++ks) {
#pragma unroll
      for (int pt = 0; pt < 4; ++pt) {
        const int prow = pt * 16 + m;
        const bf16x8 bfr =
            *(const bf16x8*)&xnv[prow * 288 + ((ks * 32 + q * 8) ^ ((prow & 7) << 3))];
        ac[pt] = __builtin_amdgcn_mfma_f32_16x16x32_bf16(wA[ks], bfr, ac[pt], 0, 0, 0);
      }
    }
#pragma unroll
    for (int r = 0; r < 4; ++r) {
      const int row = wave * 16 + q * 4 + r;
#pragma unroll
      for (int pt = 0; pt < 4; ++pt) {
        float vv = ac[pt][r] + biasv[r];
        vv = vv > 0.f ? vv + 1.f : __expf(vv);
        Kcp[row * 72 + pt * 16 + m] = f2bf(vv);
      }
    }
    __syncthreads();  // Kcp complete

    // ---- ksum partial (from activated K in LDS) ----
    {
      const int krow = tid & 255;
      const int kseg = tid >> 8;  // 0..3 -> cols kseg*16..+15
      const bf16x8 k0 = *(const bf16x8*)&Kcp[krow * 72 + kseg * 16];
      const bf16x8 k1 = *(const bf16x8*)&Kcp[krow * 72 + kseg * 16 + 8];
      float s = 0.f;
#pragma unroll
      for (int j = 0; j < 8; ++j) s += (float)k0[j] + (float)k1[j];
      ksum_acc += s;
    }

    // ---- T += K . x^T ----
#pragma unroll
    for (int ks = 0; ks < 2; ++ks) {
      bf16x8 af[4], bfv[4];
#pragma unroll
      for (int i = 0; i < 4; ++i)
        af[i] = *(const bf16x8*)&Kcp[((4 * ckg + i) * 16 + m) * 72 + ks * 32 + q * 8];
#pragma unroll
      for (int j = 0; j < 4; ++j)
        bfv[j] = *(const bf16x8*)&xcm[((4 * cvg + j) * 16 + m) * 72 + ks * 32 + q * 8];
#pragma unroll
      for (int i = 0; i < 4; ++i)
#pragma unroll
        for (int j = 0; j < 4; ++j)
          accT[i][j] = __builtin_amdgcn_mfma_f32_16x16x32_bf16(af[i], bfv[j], accT[i][j], 0, 0, 0);
    }
  }

  // ---- block epilogue ----
  atomicAdd(&ksum[b * CH + (tid & 255)], ksum_acc);
  if (mode == 0) {
    // per-wave-contiguous: full-line 1KB/instr regular stores
    float* Tp = tdst + (size_t)blockIdx.x * 65536 + wave * 4096 + lane * 4;
#pragma unroll
    for (int i = 0; i < 4; ++i)
#pragma unroll
      for (int j = 0; j < 4; ++j)
        *(f32x4*)(Tp + (i * 4 + j) * 256) = accT[i][j];
  } else {
    float* Tb2 = tdst + (size_t)b * 65536;
#pragma unroll
    for (int i = 0; i < 4; ++i)
#pragma unroll
      for (int j = 0; j < 4; ++j)
#pragma unroll
        for (int r = 0; r < 4; ++r) {
          const int row = (4 * ckg + i) * 16 + q * 4 + r;
          const int col = (4 * cvg + j) * 16 + m;
          atomicAdd(&Tb2[row * CH + col], accT[i][j][r]);
        }
  }
}

// ---------------- Traw[b] = sum of 32 per-block partials (unpermute) ----------------
__global__ __launch_bounds__(256) void treduce_kernel(const float* __restrict__ part,
                                                      float* __restrict__ Traw) {
  const int b = blockIdx.x >> 4;
  const int w = blockIdx.x & 15;
  __shared__ float tile[64][65];
  const size_t base = (size_t)w * 4096;
  for (int k = 0; k < 16; ++k) {
    const int o = k * 256 + threadIdx.x;
    float s = 0.f;
#pragma unroll 8
    for (int sp = 0; sp < 32; ++sp)
      s += __builtin_nontemporal_load(&part[(size_t)(sp * 8 + b) * 65536 + base + o]);
    const int lanef = (o >> 2) & 63;
    const int r = o & 3;
    const int e4 = o >> 8;
    const int i = e4 >> 2, j = e4 & 3;
    const int mm = lanef & 15, qq = lanef >> 4;
    tile[i * 16 + qq * 4 + r][j * 16 + mm] = s;
  }
  __syncthreads();
  const int ckg = w >> 2, cvg = w & 3;
  float* dst = Traw + (size_t)b * 65536 + (size_t)(ckg * 64) * 256 + cvg * 64;
  const int col = threadIdx.x & 63;
  const int r0 = threadIdx.x >> 6;
#pragma unroll
  for (int k = 0; k < 16; ++k) {
    const int lr = r0 * 16 + k;
    dst[(size_t)lr * 256 + col] = tile[lr][col];
  }
}

// ---------------- m1: G = (Wp*rs) . Traw ; A1 = sA*G + sB*s1 ; s1 = (Wp*rs).ksum --
__global__ __launch_bounds__(256) void m1_kernel(
    const float* __restrict__ Wp, const float* __restrict__ Traw,
    const float* __restrict__ ksum, const float* __restrict__ sA,
    const float* __restrict__ sB, float* __restrict__ A1, float* __restrict__ s1) {
  __shared__ float WpLT[256 * 16];
  __shared__ float ksL[256];
  const int b = blockIdx.x >> 4;
  const int rt = blockIdx.x & 15;
  const int tid = threadIdx.x;
  const float kk = ksum[b * 256 + tid];
  ksL[tid] = kk;
  const float rs = 1.f / (kk + ATTN_EPS);
#pragma unroll
  for (int r = 0; r < 16; ++r)
    WpLT[tid * 16 + r] = Wp[(rt * 16 + r) * 256 + tid] * rs;
  __syncthreads();
  float acc[16], s1a[16];
#pragma unroll
  for (int r = 0; r < 16; ++r) { acc[r] = 0.f; s1a[r] = 0.f; }
  const float* Tb = Traw + (size_t)b * 65536;
  for (int k = 0; k < 256; ++k) {
    const float v = Tb[k * 256 + tid];
    const float kv = ksL[k];
#pragma unroll
    for (int r4 = 0; r4 < 4; ++r4) {
      const f32x4 w4 = *(const f32x4*)&WpLT[k * 16 + r4 * 4];
#pragma unroll
      for (int e = 0; e < 4; ++e) {
        acc[r4 * 4 + e] += w4[e] * v;
        s1a[r4 * 4 + e] += w4[e] * kv;
      }
    }
  }
  const float av = sA[b * 256 + tid], sv = sB[b * 256 + tid];
#pragma unroll
  for (int r = 0; r < 16; ++r)
    A1[(size_t)b * 65536 + (rt * 16 + r) * 256 + tid] = av * acc[r] + sv * s1a[r];
  if (tid == 0) {
#pragma unroll
    for (int r = 0; r < 16; ++r) s1[b * 256 + rt * 16 + r] = s1a[r];
  }
}

// ---------------- m2: M = A1 . Wv^T + bv*s1 -> bf16 ----------------
__global__ __launch_bounds__(256) void m2_kernel(
    const float* __restrict__ A1, const float* __restrict__ Wvt,
    const float* __restrict__ bv, const float* __restrict__ s1,
    u16* __restrict__ Mb) {
  __shared__ float ALT[256 * 16];
  const int b = blockIdx.x >> 4;
  const int rt = blockIdx.x & 15;
  const int tid = threadIdx.x;
#pragma unroll
  for (int r = 0; r < 16; ++r)
    ALT[tid * 16 + r] = A1[(size_t)b * 65536 + (rt * 16 + r) * 256 + tid];
  __syncthreads();
  float acc[16];
#pragma unroll
  for (int r = 0; r < 16; ++r) acc[r] = 0.f;
  for (int ci = 0; ci < 256; ++ci) {
    const float wv = Wvt[ci * 256 + tid];
#pragma unroll
    for (int r4 = 0; r4 < 4; ++r4) {
      const f32x4 a4 = *(const f32x4*)&ALT[ci * 16 + r4 * 4];
#pragma unroll
      for (int e = 0; e < 4; ++e) acc[r4 * 4 + e] += a4[e] * wv;
    }
  }
  const float bvd = bv[tid];
#pragma unroll
  for (int r = 0; r < 16; ++r)
    Mb[(size_t)b * 65536 + (rt * 16 + r) * 256 + tid] =
        f2bf(acc[r] + bvd * s1[b * 256 + rt * 16 + r]);
}

// ---------------- out = M . (elu(Wq'.x+bq')+1) + bp + x ----------------
// grid 2048: b = bid&7 (XCD-affine), 64-pixel chunk = bid>>3. 256 thr, 36KB LDS.
// (round-3 form: the 2-chunk variant regressed 2.6x — L2 thrash on output RFO)
__global__ __launch_bounds__(256, 4) void out_kernel(
    const float* __restrict__ x, const u16* __restrict__ Wqb, const float* __restrict__ bqf,
    const u16* __restrict__ Mb, const float* __restrict__ bp, float* __restrict__ out) {
  __shared__ __align__(16) u16 buf[64 * 288];  // raw x pixel-major, then q pixel-major
  const int b = blockIdx.x & 7;
  const int pix0 = (blockIdx.x >> 3) * 64;
  const int tid = threadIdx.x;
  const int wave = tid >> 6;  // 0..3
  const int lane = tid & 63;
  const int m = lane & 15;
  const int q = lane >> 4;

  const float* xb = x + (size_t)b * CH * NPIX;
  const u16* Wqbb = Wqb + b * 65536;

  const int p_ = tid & 63;
  const int cq = tid >> 6;  // 0..3
#pragma unroll
  for (int i = 0; i < 16; ++i) {
    const int c = (cq + 4 * i) * 4;
    const float v0 = __builtin_nontemporal_load(&xb[(size_t)(c + 0) * NPIX + pix0 + p_]);
    const float v1 = __builtin_nontemporal_load(&xb[(size_t)(c + 1) * NPIX + pix0 + p_]);
    const float v2 = __builtin_nontemporal_load(&xb[(size_t)(c + 2) * NPIX + pix0 + p_]);
    const float v3 = __builtin_nontemporal_load(&xb[(size_t)(c + 3) * NPIX + pix0 + p_]);
    const unsigned int lo = (unsigned int)f2bf(v0) | ((unsigned int)f2bf(v1) << 16);
    const unsigned int hi = (unsigned int)f2bf(v2) | ((unsigned int)f2bf(v3) << 16);
    *(uint2*)&buf[p_ * 288 + (c ^ ((p_ & 7) << 3))] = make_uint2(lo, hi);
  }
  __syncthreads();

  // G3: q^T = x^T . Wq'^T  (rows = pixels, cols = c2)
  f32x4 aq[4][4];  // [pt][ct]
#pragma unroll
  for (int pt = 0; pt < 4; ++pt)
#pragma unroll
    for (int ct = 0; ct < 4; ++ct) aq[pt][ct] = {0.f, 0.f, 0.f, 0.f};
#pragma unroll
  for (int ks = 0; ks < 8; ++ks) {
    bf16x8 af[4];
#pragma unroll
    for (int pt = 0; pt < 4; ++pt) {
      const int prow = pt * 16 + m;
      af[pt] = *(const bf16x8*)&buf[prow * 288 + ((ks * 32 + q * 8) ^ ((prow & 7) << 3))];
    }
#pragma unroll
    for (int ct = 0; ct < 4; ++ct) {
      const bf16x8 bfr = *(const bf16x8*)(Wqbb + ((4 * wave + ct) * 16 + m) * 256 + ks * 32 + q * 8);
#pragma unroll
      for (int pt = 0; pt < 4; ++pt)
        aq[pt][ct] = __builtin_amdgcn_mfma_f32_16x16x32_bf16(af[pt], bfr, aq[pt][ct], 0, 0, 0);
    }
  }
  __syncthreads();  // all x reads done; reuse buf for q
#pragma unroll
  for (int ct = 0; ct < 4; ++ct) {
    const int c2 = (4 * wave + ct) * 16 + m;
    const float bias = bqf[b * 256 + c2];
#pragma unroll
    for (int pt = 0; pt < 4; ++pt)
#pragma unroll
      for (int r = 0; r < 4; ++r) {
        float v = aq[pt][ct][r] + bias;
        v = v > 0.f ? v + 1.f : __expf(v);
        const int prow = pt * 16 + q * 4 + r;
        buf[prow * 288 + (c2 ^ ((prow & 7) << 3))] = f2bf(v);
      }
  }
  __syncthreads();

  // G4: out = M . q
  f32x4 ao[4][4];  // [ct][pt]
#pragma unroll
  for (int ct = 0; ct < 4; ++ct)
#pragma unroll
    for (int pt = 0; pt < 4; ++pt) ao[ct][pt] = {0.f, 0.f, 0.f, 0.f};
  const u16* Ab = Mb + (size_t)b * 65536;
#pragma unroll
  for (int ks = 0; ks < 8; ++ks) {
    bf16x8 af2[4];
#pragma unroll
    for (int ct = 0; ct < 4; ++ct)
      af2[ct] = *(const bf16x8*)(Ab + ((4 * wave + ct) * 16 + m) * 256 + ks * 32 + q * 8);
#pragma unroll
    for (int pt = 0; pt < 4; ++pt) {
      const int brow = pt * 16 + m;
      const bf16x8 bfr = *(const bf16x8*)&buf[brow * 288 + ((ks * 32 + q * 8) ^ ((brow & 7) << 3))];
#pragma unroll
      for (int ct = 0; ct < 4; ++ct)
        ao[ct][pt] = __builtin_amdgcn_mfma_f32_16x16x32_bf16(af2[ct], bfr, ao[ct][pt], 0, 0, 0);
    }
  }
  float* ob = out + (size_t)b * CH * NPIX;
#pragma unroll
  for (int ct = 0; ct < 4; ++ct)
#pragma unroll
    for (int r = 0; r < 4; ++r) {
      const int row = (4 * wave + ct) * 16 + q * 4 + r;
      const float bias = bp[row];
#pragma unroll
      for (int pt = 0; pt < 4; ++pt) {
        const int idx = row * NPIX + pix0 + pt * 16 + m;
        const float xr = __builtin_nontemporal_load(&xb[idx]);
        ob[idx] = ao[ct][pt][r] + bias + xr;
      }
    }
}

// ---------------- launch ----------------
extern "C" void kernel_launch(void* const* d_in, const int* in_sizes, int n_in,
                              void* d_out, int out_size, void* d_ws, size_t ws_size,
                              hipStream_t stream) {
  const float* x     = (const float*)d_in[0];
  const float* gamma = (const float*)d_in[1];
  const float* beta  = (const float*)d_in[2];
  const float* Wq    = (const float*)d_in[3];
  const float* bq    = (const float*)d_in[4];
  const float* Wk    = (const float*)d_in[5];
  const float* bk    = (const float*)d_in[6];
  const float* Wv    = (const float*)d_in[7];
  const float* bv    = (const float*)d_in[8];
  const float* Wp    = (const float*)d_in[9];
  const float* bp    = (const float*)d_in[10];
  float* out = (float*)d_out;

  float* wsf  = (float*)d_ws;
  float* sum  = wsf;                 // 64
  float* sqs  = wsf + 64;            // 64
  float* ksum = wsf + 128;           // 2048
  float* sA   = wsf + 2176;          // 2048
  float* sB   = wsf + 4224;          // 2048
  float* s1   = wsf + 6272;          // 2048
  float* bkf  = wsf + 8320;          // 2048
  float* bqf  = wsf + 10368;         // 2048
  float* Wvt  = wsf + 12416;         // 65536
  float* Traw = wsf + 77952;         // 524288
  float* A1   = wsf + 602240;        // 524288
  u16* Wqb = (u16*)(wsf + 1126528);  // 524288 u16
  u16* Wkb = Wqb + 524288;           // 524288 u16
  u16* Mb  = (u16*)(wsf + 1650816);  // 524288 u16 (layout ends ~7.65 MB)

  // T partials (256 x 64K floats = 64 MiB) at the 8 MiB mark, if workspace allows.
  const bool bigws = ws_size >= ((size_t)72 << 20);
  float* Tpart = bigws ? (wsf + ((size_t)1 << 21)) : Traw;
  const int mode = bigws ? 0 : 1;

  // zero atomic targets (sum/sqs/ksum); mode 1 additionally zeroes Traw.
  hipMemsetAsync(wsf, 0, (size_t)(bigws ? 2176 : 602240) * sizeof(float), stream);
  stats_kernel<<<512, 256, 0, stream>>>(x, sum, sqs);
  finalize_kernel<<<264, 256, 0, stream>>>(sum, sqs, gamma, beta, sA, sB, Wv, Wvt);
  foldw_kernel<<<128, 256, 0, stream>>>(Wq, bq, Wk, bk, sA, sB, Wqb, Wkb, bqf, bkf);
  fused_t_kernel<<<256, 1024, 0, stream>>>(x, Wkb, bkf, ksum, Tpart, mode);
  if (bigws) treduce_kernel<<<128, 256, 0, stream>>>(Tpart, Traw);
  m1_kernel<<<128, 256, 0, stream>>>(Wp, Traw, ksum, sA, sB, A1, s1);
  m2_kernel<<<128, 256, 0, stream>>>(A1, Wvt, bv, s1, Mb);
  out_kernel<<<2048, 256, 0, stream>>>(x, Wqb, bqf, Mb, bp, out);
}

// Round 6
// 598.556 us; speedup vs baseline: 1.3896x; 1.1022x over previous
//
#include <hip/hip_runtime.h>

typedef unsigned short u16;
using bf16x8 = __attribute__((ext_vector_type(8))) __bf16;
using f32x4  = __attribute__((ext_vector_type(4))) float;

#define BATCH 8
#define CH    256
#define NPIX  16384
#define GN_EPS   1e-5f
#define ATTN_EPS 1e-6f

__device__ __forceinline__ u16 f2bf(float f) {
  unsigned int u = __float_as_uint(f);
  u += 0x7fffu + ((u >> 16) & 1u);
  return (u16)(u >> 16);
}

// ---------------- GroupNorm stats: per (b,g) sum / sumsq ----------------
__global__ void stats_kernel(const float* __restrict__ x, float* __restrict__ sum,
                             float* __restrict__ sqs) {
  const int gi = blockIdx.x >> 3;   // 0..63  (b*8+g)
  const int sp = blockIdx.x & 7;    // split
  const float4* p = (const float4*)x + (size_t)gi * 131072 + (size_t)sp * 16384;
  float s = 0.f, ss = 0.f;
  for (int i = 0; i < 64; ++i) {
    float4 v = p[threadIdx.x + i * 256];
    s  += v.x + v.y + v.z + v.w;
    ss += v.x * v.x + v.y * v.y + v.z * v.z + v.w * v.w;
  }
  for (int off = 32; off; off >>= 1) {
    s  += __shfl_xor(s, off);
    ss += __shfl_xor(ss, off);
  }
  __shared__ float rs[4], rss[4];
  const int wave = threadIdx.x >> 6, lane = threadIdx.x & 63;
  if (!lane) { rs[wave] = s; rss[wave] = ss; }
  __syncthreads();
  if (!threadIdx.x) {
    atomicAdd(&sum[gi], rs[0] + rs[1] + rs[2] + rs[3]);
    atomicAdd(&sqs[gi], rss[0] + rss[1] + rss[2] + rss[3]);
  }
}

// ---------------- prep: fold GN into Wq/Wk (+bias dots), sA/sB, Wv transpose ----
// blocks 0..127: foldw for (b = bid>>4, rowtile = bid&15); rt==0 also stores sA/sB.
// blocks 128..383: Wvt[ci][d] = Wv[d][ci].
__global__ __launch_bounds__(256) void prep_kernel(
    const float* __restrict__ sums, const float* __restrict__ sqs,
    const float* __restrict__ gamma, const float* __restrict__ beta,
    const float* __restrict__ Wq, const float* __restrict__ bq,
    const float* __restrict__ Wk, const float* __restrict__ bk,
    const float* __restrict__ Wv,
    u16* __restrict__ Wqb, u16* __restrict__ Wkb,
    float* __restrict__ bqf, float* __restrict__ bkf,
    float* __restrict__ sA, float* __restrict__ sB, float* __restrict__ Wvt) {
  if (blockIdx.x < 128) {
    const int b = blockIdx.x >> 4;
    const int rt = blockIdx.x & 15;
    const int tid = threadIdx.x;
    const int wave = tid >> 6, lane = tid & 63;
    // recompute per-(b,c) scale/shift locally (finalize folded in)
    const int gi = b * 8 + (tid >> 5);
    const float inv = 1.f / 524288.f;
    const float mean = sums[gi] * inv;
    const float var = sqs[gi] * inv - mean * mean;
    const float rstd = rsqrtf(var + GN_EPS);
    const float a = rstd * gamma[tid];
    const float s = beta[tid] - mean * a;
    if (rt == 0) { sA[b * 256 + tid] = a; sB[b * 256 + tid] = s; }
    __shared__ float rq[4], rk[4];
    for (int i = 0; i < 16; ++i) {
      const int row = rt * 16 + i;
      const float wq = Wq[row * 256 + tid];
      const float wk = Wk[row * 256 + tid];
      Wqb[b * 65536 + row * 256 + tid] = f2bf(wq * a);
      Wkb[b * 65536 + row * 256 + tid] = f2bf(wk * a);
      float pq = wq * s, pk = wk * s;
      for (int off = 32; off; off >>= 1) {
        pq += __shfl_xor(pq, off);
        pk += __shfl_xor(pk, off);
      }
      if (!lane) { rq[wave] = pq; rk[wave] = pk; }
      __syncthreads();
      if (!tid) {
        bqf[b * 256 + row] = bq[row] + rq[0] + rq[1] + rq[2] + rq[3];
        bkf[b * 256 + row] = bk[row] + rk[0] + rk[1] + rk[2] + rk[3];
      }
      __syncthreads();
    }
  } else {
    __shared__ float t[16][17];
    const int bid = blockIdx.x - 128;
    const int ti = bid & 15, tj = bid >> 4;
    const int tx = threadIdx.x & 15, ty = threadIdx.x >> 4;
    t[ty][tx] = Wv[(tj * 16 + ty) * 256 + ti * 16 + tx];
    __syncthreads();
    Wvt[(ti * 16 + ty) * 256 + tj * 16 + tx] = t[tx][ty];
  }
}

// ---------------- fused: raw x -> K conv -> Traw += K.x^T, ksum ----------------
// grid 256 = 8b x 32sp (b = bid&7, XCD-affine), 1024 threads / 16 waves.
// Wk' fragments register-hoisted (32 VGPR, loop-invariant) -> zero weight loads
// in the chunk loop. NO register prefetch of x (round-5 lesson: it spilled to
// scratch under the 64-arch-VGPR allocation -> +300MB of spill traffic).
__global__ __launch_bounds__(1024, 4) void fused_t_kernel(
    const float* __restrict__ x, const u16* __restrict__ Wkb, const float* __restrict__ bkf,
    float* __restrict__ ksum, float* __restrict__ tdst, int mode) {
  __shared__ __align__(16) u16 xnv[64 * 288];  // raw x pixel-major [p][c], c XOR-swizzled
  __shared__ __align__(16) u16 xcm[256 * 72];  // raw x c-major [c][p]
  __shared__ __align__(16) u16 Kcp[256 * 72];  // activated K, c-major [c][p]

  const int b  = blockIdx.x & 7;
  const int sp = blockIdx.x >> 3;
  const int tid = threadIdx.x;
  const int wave = tid >> 6;   // 0..15 = c_out tile
  const int lane = tid & 63;
  const int m = lane & 15;
  const int q = lane >> 4;

  const int ckg = wave >> 2;   // T: k-row tiles [4ckg..+3]
  const int cvg = wave & 3;    // T: ci tiles  [4cvg..+3]

  const float* xb = x + (size_t)b * CH * NPIX;
  const u16* Wkbb = Wkb + b * 65536;

  // ---- hoist this wave's Wk' fragments: 8 x bf16x8 = 32 VGPR, loop-invariant ----
  bf16x8 wA[8];
#pragma unroll
  for (int ks = 0; ks < 8; ++ks)
    wA[ks] = *(const bf16x8*)(Wkbb + (wave * 16 + m) * 256 + ks * 32 + q * 8);

  float biasv[4];
#pragma unroll
  for (int r = 0; r < 4; ++r) biasv[r] = bkf[b * 256 + wave * 16 + q * 4 + r];

  f32x4 accT[4][4];
#pragma unroll
  for (int i = 0; i < 4; ++i)
#pragma unroll
    for (int j = 0; j < 4; ++j) accT[i][j] = {0.f, 0.f, 0.f, 0.f};
  float ksum_acc = 0.f;

  const int p_ = tid & 63;
  const int cq = tid >> 6;  // 0..15

  for (int ch = 0; ch < 8; ++ch) {
    const int pix0 = sp * 512 + ch * 64;
    __syncthreads();  // prev T-phase reads done; buffers free
    // ---- stage raw x -> bf16, both layouts ----
#pragma unroll
    for (int i = 0; i < 4; ++i) {
      const int c = (cq + 16 * i) * 4;
      const float v0 = __builtin_nontemporal_load(&xb[(size_t)(c + 0) * NPIX + pix0 + p_]);
      const float v1 = __builtin_nontemporal_load(&xb[(size_t)(c + 1) * NPIX + pix0 + p_]);
      const float v2 = __builtin_nontemporal_load(&xb[(size_t)(c + 2) * NPIX + pix0 + p_]);
      const float v3 = __builtin_nontemporal_load(&xb[(size_t)(c + 3) * NPIX + pix0 + p_]);
      const u16 b0 = f2bf(v0), b1 = f2bf(v1), b2 = f2bf(v2), b3 = f2bf(v3);
      const unsigned int lo = (unsigned int)b0 | ((unsigned int)b1 << 16);
      const unsigned int hi = (unsigned int)b2 | ((unsigned int)b3 << 16);
      *(uint2*)&xnv[p_ * 288 + (c ^ ((p_ & 7) << 3))] = make_uint2(lo, hi);
      xcm[(c + 0) * 72 + p_] = b0;
      xcm[(c + 1) * 72 + p_] = b1;
      xcm[(c + 2) * 72 + p_] = b2;
      xcm[(c + 3) * 72 + p_] = b3;
    }
    __syncthreads();

    // ---- K = elu(Wk' . x + bk') + 1 -> Kcp ; 1 c-tile x 4 pixel tiles/wave ----
    f32x4 ac[4];
#pragma unroll
    for (int pt = 0; pt < 4; ++pt) ac[pt] = {0.f, 0.f, 0.f, 0.f};
#pragma unroll
    for (int ks = 0; ks < 8; ++ks) {
#pragma unroll
      for (int pt = 0; pt < 4; ++pt) {
        const int prow = pt * 16 + m;
        const bf16x8 bfr =
            *(const bf16x8*)&xnv[prow * 288 + ((ks * 32 + q * 8) ^ ((prow & 7) << 3))];
        ac[pt] = __builtin_amdgcn_mfma_f32_16x16x32_bf16(wA[ks], bfr, ac[pt], 0, 0, 0);
      }
    }
#pragma unroll
    for (int r = 0; r < 4; ++r) {
      const int row = wave * 16 + q * 4 + r;
#pragma unroll
      for (int pt = 0; pt < 4; ++pt) {
        float v = ac[pt][r] + biasv[r];
        v = v > 0.f ? v + 1.f : __expf(v);
        Kcp[row * 72 + pt * 16 + m] = f2bf(v);
      }
    }
    __syncthreads();  // Kcp complete

    // ---- ksum partial (from activated K in LDS) ----
    {
      const int krow = tid & 255;
      const int kseg = tid >> 8;  // 0..3 -> cols kseg*16..+15
      const bf16x8 k0 = *(const bf16x8*)&Kcp[krow * 72 + kseg * 16];
      const bf16x8 k1 = *(const bf16x8*)&Kcp[krow * 72 + kseg * 16 + 8];
      float s = 0.f;
#pragma unroll
      for (int j = 0; j < 8; ++j) s += (float)k0[j] + (float)k1[j];
      ksum_acc += s;
    }

    // ---- T += K . x^T ----
#pragma unroll
    for (int ks = 0; ks < 2; ++ks) {
      bf16x8 af[4], bfv[4];
#pragma unroll
      for (int i = 0; i < 4; ++i)
        af[i] = *(const bf16x8*)&Kcp[((4 * ckg + i) * 16 + m) * 72 + ks * 32 + q * 8];
#pragma unroll
      for (int j = 0; j < 4; ++j)
        bfv[j] = *(const bf16x8*)&xcm[((4 * cvg + j) * 16 + m) * 72 + ks * 32 + q * 8];
#pragma unroll
      for (int i = 0; i < 4; ++i)
#pragma unroll
        for (int j = 0; j < 4; ++j)
          accT[i][j] = __builtin_amdgcn_mfma_f32_16x16x32_bf16(af[i], bfv[j], accT[i][j], 0, 0, 0);
    }
  }

  // ---- block epilogue ----
  atomicAdd(&ksum[b * CH + (tid & 255)], ksum_acc);
  if (mode == 0) {
    // per-wave-contiguous: full-line 1KB/instr regular stores
    float* Tp = tdst + (size_t)blockIdx.x * 65536 + wave * 4096 + lane * 4;
#pragma unroll
    for (int i = 0; i < 4; ++i)
#pragma unroll
      for (int j = 0; j < 4; ++j)
        *(f32x4*)(Tp + (i * 4 + j) * 256) = accT[i][j];
  } else {
    float* Tb2 = tdst + (size_t)b * 65536;
#pragma unroll
    for (int i = 0; i < 4; ++i)
#pragma unroll
      for (int j = 0; j < 4; ++j)
#pragma unroll
        for (int r = 0; r < 4; ++r) {
          const int row = (4 * ckg + i) * 16 + q * 4 + r;
          const int col = (4 * cvg + j) * 16 + m;
          atomicAdd(&Tb2[row * CH + col], accT[i][j][r]);
        }
  }
}

// ---------------- Traw[b] = sum of 32 per-block partials (unpermute) ----------------
__global__ __launch_bounds__(256) void treduce_kernel(const float* __restrict__ part,
                                                      float* __restrict__ Traw) {
  const int b = blockIdx.x >> 4;
  const int w = blockIdx.x & 15;
  __shared__ float tile[64][65];
  const size_t base = (size_t)w * 4096;
  for (int k = 0; k < 16; ++k) {
    const int o = k * 256 + threadIdx.x;
    float s = 0.f;
#pragma unroll 8
    for (int sp = 0; sp < 32; ++sp)
      s += __builtin_nontemporal_load(&part[(size_t)(sp * 8 + b) * 65536 + base + o]);
    const int lanef = (o >> 2) & 63;
    const int r = o & 3;
    const int e4 = o >> 8;
    const int i = e4 >> 2, j = e4 & 3;
    const int mm = lanef & 15, qq = lanef >> 4;
    tile[i * 16 + qq * 4 + r][j * 16 + mm] = s;
  }
  __syncthreads();
  const int ckg = w >> 2, cvg = w & 3;
  float* dst = Traw + (size_t)b * 65536 + (size_t)(ckg * 64) * 256 + cvg * 64;
  const int col = threadIdx.x & 63;
  const int r0 = threadIdx.x >> 6;
#pragma unroll
  for (int k = 0; k < 16; ++k) {
    const int lr = r0 * 16 + k;
    dst[(size_t)lr * 256 + col] = tile[lr][col];
  }
}

// ---------------- m12: A1-tile = sA*((Wp*rs).Traw) + sB*s1 (LDS), then
//                  M = A1 . Wv^T + bv*s1 -> bf16.  (m1+m2 merged; A1/s1 never
//                  touch global. s1a is redundantly identical across threads.)
__global__ __launch_bounds__(256) void m12_kernel(
    const float* __restrict__ Wp, const float* __restrict__ Traw,
    const float* __restrict__ ksum, const float* __restrict__ sA,
    const float* __restrict__ sB, const float* __restrict__ Wvt,
    const float* __restrict__ bv, u16* __restrict__ Mb) {
  __shared__ float WpLT[256 * 16];  // [k][r], pre-scaled by rs
  __shared__ float ksL[256];
  __shared__ float A1T[256 * 16];   // [ci][r]
  const int b = blockIdx.x >> 4;
  const int rt = blockIdx.x & 15;
  const int tid = threadIdx.x;
  const float kk = ksum[b * 256 + tid];
  ksL[tid] = kk;
  const float rs = 1.f / (kk + ATTN_EPS);
#pragma unroll
  for (int r = 0; r < 16; ++r)
    WpLT[tid * 16 + r] = Wp[(rt * 16 + r) * 256 + tid] * rs;
  __syncthreads();
  float acc[16], s1a[16];
#pragma unroll
  for (int r = 0; r < 16; ++r) { acc[r] = 0.f; s1a[r] = 0.f; }
  const float* Tb = Traw + (size_t)b * 65536;
  for (int k = 0; k < 256; ++k) {
    const float v = Tb[k * 256 + tid];
    const float kv = ksL[k];
#pragma unroll
    for (int r4 = 0; r4 < 4; ++r4) {
      const f32x4 w4 = *(const f32x4*)&WpLT[k * 16 + r4 * 4];
#pragma unroll
      for (int e = 0; e < 4; ++e) {
        acc[r4 * 4 + e] += w4[e] * v;
        s1a[r4 * 4 + e] += w4[e] * kv;
      }
    }
  }
  const float av = sA[b * 256 + tid], sv = sB[b * 256 + tid];
#pragma unroll
  for (int r = 0; r < 16; ++r)
    A1T[tid * 16 + r] = av * acc[r] + sv * s1a[r];
  __syncthreads();
  // ---- m2 half: M[rt*16+r][tid] = sum_ci A1T[ci][r]*Wvt[ci][tid] + bv[tid]*s1a[r]
  float acc2[16];
#pragma unroll
  for (int r = 0; r < 16; ++r) acc2[r] = 0.f;
  for (int ci = 0; ci < 256; ++ci) {
    const float wv = Wvt[ci * 256 + tid];
#pragma unroll
    for (int r4 = 0; r4 < 4; ++r4) {
      const f32x4 a4 = *(const f32x4*)&A1T[ci * 16 + r4 * 4];  // uniform: LDS broadcast
#pragma unroll
      for (int e = 0; e < 4; ++e) acc2[r4 * 4 + e] += a4[e] * wv;
    }
  }
  const float bvd = bv[tid];
#pragma unroll
  for (int r = 0; r < 16; ++r)
    Mb[(size_t)b * 65536 + (rt * 16 + r) * 256 + tid] = f2bf(acc2[r] + bvd * s1a[r]);
}

// ---------------- out = M . (elu(Wq'.x+bq')+1) + bp + x ----------------
// grid 2048: b = bid&7 (XCD-affine), 64-pixel chunk = bid>>3. 256 thr, 36KB LDS.
__global__ __launch_bounds__(256, 4) void out_kernel(
    const float* __restrict__ x, const u16* __restrict__ Wqb, const float* __restrict__ bqf,
    const u16* __restrict__ Mb, const float* __restrict__ bp, float* __restrict__ out) {
  __shared__ __align__(16) u16 buf[64 * 288];  // raw x pixel-major, then q pixel-major
  const int b = blockIdx.x & 7;
  const int pix0 = (blockIdx.x >> 3) * 64;
  const int tid = threadIdx.x;
  const int wave = tid >> 6;  // 0..3
  const int lane = tid & 63;
  const int m = lane & 15;
  const int q = lane >> 4;

  const float* xb = x + (size_t)b * CH * NPIX;
  const u16* Wqbb = Wqb + b * 65536;

  const int p_ = tid & 63;
  const int cq = tid >> 6;  // 0..3
#pragma unroll
  for (int i = 0; i < 16; ++i) {
    const int c = (cq + 4 * i) * 4;
    const float v0 = __builtin_nontemporal_load(&xb[(size_t)(c + 0) * NPIX + pix0 + p_]);
    const float v1 = __builtin_nontemporal_load(&xb[(size_t)(c + 1) * NPIX + pix0 + p_]);
    const float v2 = __builtin_nontemporal_load(&xb[(size_t)(c + 2) * NPIX + pix0 + p_]);
    const float v3 = __builtin_nontemporal_load(&xb[(size_t)(c + 3) * NPIX + pix0 + p_]);
    const unsigned int lo = (unsigned int)f2bf(v0) | ((unsigned int)f2bf(v1) << 16);
    const unsigned int hi = (unsigned int)f2bf(v2) | ((unsigned int)f2bf(v3) << 16);
    *(uint2*)&buf[p_ * 288 + (c ^ ((p_ & 7) << 3))] = make_uint2(lo, hi);
  }
  __syncthreads();

  // G3: q^T = x^T . Wq'^T  (rows = pixels, cols = c2)
  f32x4 aq[4][4];  // [pt][ct]
#pragma unroll
  for (int pt = 0; pt < 4; ++pt)
#pragma unroll
    for (int ct = 0; ct < 4; ++ct) aq[pt][ct] = {0.f, 0.f, 0.f, 0.f};
#pragma unroll
  for (int ks = 0; ks < 8; ++ks) {
    bf16x8 af[4];
#pragma unroll
    for (int pt = 0; pt < 4; ++pt) {
      const int prow = pt * 16 + m;
      af[pt] = *(const bf16x8*)&buf[prow * 288 + ((ks * 32 + q * 8) ^ ((prow & 7) << 3))];
    }
#pragma unroll
    for (int ct = 0; ct < 4; ++ct) {
      const bf16x8 bfr = *(const bf16x8*)(Wqbb + ((4 * wave + ct) * 16 + m) * 256 + ks * 32 + q * 8);
#pragma unroll
      for (int pt = 0; pt < 4; ++pt)
        aq[pt][ct] = __builtin_amdgcn_mfma_f32_16x16x32_bf16(af[pt], bfr, aq[pt][ct], 0, 0, 0);
    }
  }
  __syncthreads();  // all x reads done; reuse buf for q
#pragma unroll
  for (int ct = 0; ct < 4; ++ct) {
    const int c2 = (4 * wave + ct) * 16 + m;
    const float bias = bqf[b * 256 + c2];
#pragma unroll
    for (int pt = 0; pt < 4; ++pt)
#pragma unroll
      for (int r = 0; r < 4; ++r) {
        float v = aq[pt][ct][r] + bias;
        v = v > 0.f ? v + 1.f : __expf(v);
        const int prow = pt * 16 + q * 4 + r;
        buf[prow * 288 + (c2 ^ ((prow & 7) << 3))] = f2bf(v);
      }
  }
  __syncthreads();

  // G4: out = M . q
  f32x4 ao[4][4];  // [ct][pt]
#pragma unroll
  for (int ct = 0; ct < 4; ++ct)
#pragma unroll
    for (int pt = 0; pt < 4; ++pt) ao[ct][pt] = {0.f, 0.f, 0.f, 0.f};
  const u16* Ab = Mb + (size_t)b * 65536;
#pragma unroll
  for (int ks = 0; ks < 8; ++ks) {
    bf16x8 af2[4];
#pragma unroll
    for (int ct = 0; ct < 4; ++ct)
      af2[ct] = *(const bf16x8*)(Ab + ((4 * wave + ct) * 16 + m) * 256 + ks * 32 + q * 8);
#pragma unroll
    for (int pt = 0; pt < 4; ++pt) {
      const int brow = pt * 16 + m;
      const bf16x8 bfr = *(const bf16x8*)&buf[brow * 288 + ((ks * 32 + q * 8) ^ ((brow & 7) << 3))];
#pragma unroll
      for (int ct = 0; ct < 4; ++ct)
        ao[ct][pt] = __builtin_amdgcn_mfma_f32_16x16x32_bf16(af2[ct], bfr, ao[ct][pt], 0, 0, 0);
    }
  }
  float* ob = out + (size_t)b * CH * NPIX;
#pragma unroll
  for (int ct = 0; ct < 4; ++ct)
#pragma unroll
    for (int r = 0; r < 4; ++r) {
      const int row = (4 * wave + ct) * 16 + q * 4 + r;
      const float bias = bp[row];
#pragma unroll
      for (int pt = 0; pt < 4; ++pt) {
        const int idx = row * NPIX + pix0 + pt * 16 + m;
        const float xr = __builtin_nontemporal_load(&xb[idx]);
        ob[idx] = ao[ct][pt][r] + bias + xr;
      }
    }
}

// ---------------- launch ----------------
extern "C" void kernel_launch(void* const* d_in, const int* in_sizes, int n_in,
                              void* d_out, int out_size, void* d_ws, size_t ws_size,
                              hipStream_t stream) {
  const float* x     = (const float*)d_in[0];
  const float* gamma = (const float*)d_in[1];
  const float* beta  = (const float*)d_in[2];
  const float* Wq    = (const float*)d_in[3];
  const float* bq    = (const float*)d_in[4];
  const float* Wk    = (const float*)d_in[5];
  const float* bk    = (const float*)d_in[6];
  const float* Wv    = (const float*)d_in[7];
  const float* bv    = (const float*)d_in[8];
  const float* Wp    = (const float*)d_in[9];
  const float* bp    = (const float*)d_in[10];
  float* out = (float*)d_out;

  float* wsf  = (float*)d_ws;
  float* sum  = wsf;                 // 64
  float* sqs  = wsf + 64;            // 64
  float* ksum = wsf + 128;           // 2048
  float* sA   = wsf + 2176;          // 2048
  float* sB   = wsf + 4224;          // 2048
  float* bkf  = wsf + 8320;          // 2048
  float* bqf  = wsf + 10368;         // 2048
  float* Wvt  = wsf + 12416;         // 65536
  float* Traw = wsf + 77952;         // 524288
  u16* Wqb = (u16*)(wsf + 1126528);  // 524288 u16
  u16* Wkb = Wqb + 524288;           // 524288 u16
  u16* Mb  = (u16*)(wsf + 1650816);  // 524288 u16 (layout ends ~7.65 MB)

  // T partials (256 x 64K floats = 64 MiB) at the 8 MiB mark, if workspace allows.
  const bool bigws = ws_size >= ((size_t)72 << 20);
  float* Tpart = bigws ? (wsf + ((size_t)1 << 21)) : Traw;
  const int mode = bigws ? 0 : 1;

  // zero atomic targets (sum/sqs/ksum); mode 1 additionally zeroes Traw.
  hipMemsetAsync(wsf, 0, (size_t)(bigws ? 2176 : 602240) * sizeof(float), stream);
  stats_kernel<<<512, 256, 0, stream>>>(x, sum, sqs);
  prep_kernel<<<384, 256, 0, stream>>>(sum, sqs, gamma, beta, Wq, bq, Wk, bk, Wv,
                                       Wqb, Wkb, bqf, bkf, sA, sB, Wvt);
  fused_t_kernel<<<256, 1024, 0, stream>>>(x, Wkb, bkf, ksum, Tpart, mode);
  if (bigws) treduce_kernel<<<128, 256, 0, stream>>>(Tpart, Traw);
  m12_kernel<<<128, 256, 0, stream>>>(Wp, Traw, ksum, sA, sB, Wvt, bv, Mb);
  out_kernel<<<2048, 256, 0, stream>>>(x, Wqb, bqf, Mb, bp, out);
}